// Round 7
// baseline (212.939 us; speedup 1.0000x reference)
//
#include <hip/hip_runtime.h>
#include <cstdint>
#include <cstddef>

#define EPS 1e-8f

// Fixed problem instance
#define Bsz 8
#define Nn  5
#define Kk  5
#define Ll  128
#define Ff  768
#define Tt  11                 // 2N+1
#define KL  640                // K*L
#define ROWS_PER_B 2560        // N*Q*L
#define NROWS 20480
#define F4  192                // Ff/4
#define BN  40                 // B*N

// ---- stage1 geometry ----
#define S1_ROWS 16
#define S1_CH   (KL / S1_ROWS)     // 40 chunks per bn
#define S1_NBLK (BN * S1_CH)       // 1600 blocks
#define PART_STRIDE (3 * Ff)       // 2304 floats per record [B|I|All]
#define PART_STRIDE4 (PART_STRIDE / 4)  // 576

typedef float v2f __attribute__((ext_vector_type(2)));

// ---------------- Stage 1: masked partial sums ----------------
// 1600 blocks x 192 threads. Lane owns one float4 column; 16 rows per block,
// ALL 16 loads issued up-front (16 KB/lane in flight). Records {B,I,All}.
__global__ __launch_bounds__(192) void stage1(
    const float* __restrict__ sup,      // [B][N][K][L][F]
    const int*   __restrict__ Bm,       // [B][N][K][L]
    const int*   __restrict__ Im,
    float* __restrict__ part,           // [S1_NBLK][3][Ff]
    float* __restrict__ pcnt)           // [S1_NBLK][2]
{
    int blk = blockIdx.x;
    int bn  = blk / S1_CH;
    int ch  = blk - bn * S1_CH;
    int tid = threadIdx.x;

    const float4* sp = (const float4*)(sup + ((size_t)bn * KL + ch * S1_ROWS) * Ff) + tid;
    const int*    bp = Bm + bn * KL + ch * S1_ROWS;   // block-uniform
    const int*    ip = Im + bn * KL + ch * S1_ROWS;

    float4 v[S1_ROWS];
    #pragma unroll
    for (int p = 0; p < S1_ROWS; ++p) v[p] = sp[p * F4];

    int mb[S1_ROWS], mi[S1_ROWS];
    #pragma unroll
    for (int p = 0; p < S1_ROWS; ++p) { mb[p] = bp[p]; mi[p] = ip[p]; }

    v2f tB0 = {0.f,0.f}, tB1 = tB0, tI0 = tB0, tI1 = tB0, tA0 = tB0, tA1 = tB0;
    int cB = 0, cI = 0;

    #pragma unroll
    for (int p = 0; p < S1_ROWS; ++p) {
        v2f lo = {v[p].x, v[p].y};
        v2f hi = {v[p].z, v[p].w};
        tA0 += lo; tA1 += hi;
        if (mb[p]) { tB0 += lo; tB1 += hi; ++cB; }
        if (mi[p]) { tI0 += lo; tI1 += hi; ++cI; }
    }

    float4* o = (float4*)(part + (size_t)blk * PART_STRIDE);
    float4 rB = {tB0.x, tB0.y, tB1.x, tB1.y};
    float4 rI = {tI0.x, tI0.y, tI1.x, tI1.y};
    float4 rA = {tA0.x, tA0.y, tA1.x, tA1.y};
    o[tid]          = rB;
    o[F4 + tid]     = rI;
    o[2 * F4 + tid] = rA;

    if (tid == 0) {
        pcnt[2 * (size_t)blk]     = (float)cB;
        pcnt[2 * (size_t)blk + 1] = (float)cI;
    }
}

// ---------------- Stage 2: reduce 40 chunks -> bnsum ----------------
// 90 blocks x 256 = 23,040 threads = one per (bn, set in {B,I,All}, f4).
__global__ __launch_bounds__(256) void stage2(
    const float* __restrict__ part,     // [S1_NBLK][3][Ff]
    float* __restrict__ bnsum,          // [BN][3][Ff]
    float* __restrict__ loss_out)
{
    int gid = blockIdx.x * 256 + threadIdx.x;
    if (gid == 0) loss_out[0] = 0.0f;

    int bn  = gid / (3 * F4);
    int r   = gid - bn * (3 * F4);
    int set = r / F4;
    int f4  = r - set * F4;

    const float4* src = (const float4*)(part + (size_t)bn * S1_CH * PART_STRIDE + set * Ff) + f4;
    float4 s = {0, 0, 0, 0};
    #pragma unroll
    for (int c8 = 0; c8 < S1_CH / 8; ++c8) {
        float4 v[8];
        #pragma unroll
        for (int j = 0; j < 8; ++j) v[j] = src[(size_t)(c8 * 8 + j) * PART_STRIDE4];
        #pragma unroll
        for (int j = 0; j < 8; ++j) {
            s.x += v[j].x; s.y += v[j].y; s.z += v[j].z; s.w += v[j].w;
        }
    }
    ((float4*)bnsum)[((size_t)bn * 3 + set) * F4 + f4] = s;
}

// ---------------- Stage 3: normalize + logits + argmax + NLL ----------------
// 640 blocks x 256 threads (4 waves) = 2560 waves (2.5/SIMD). Block covers 32
// rows; thread = 1 row x 1/8-row slice (24 float4). lane = 8*p + s.
// LDS proto [t][8][25] float4: slice s starts 100 banks ~ 4*(s) bank-quads
// apart -> conflict-free 8-lane broadcasts. Query loads batched 12-deep.
#define S3_ROWS 32
#define S3_NBLK (NROWS / S3_ROWS)          // 640
#define BLKS_PER_B (ROWS_PER_B / S3_ROWS)  // 80
#define SL  8                               // slices
#define SW  24                              // float4 per slice
#define LDS_T (SL * (SW + 1))               // 200 float4 per tag

__global__ __launch_bounds__(256) void stage3(
    const float* __restrict__ query,    // [B][2560][Ff]
    const float* __restrict__ bnsum,    // [BN][3][Ff]
    const float* __restrict__ pcnt,     // [S1_NBLK][2]
    const int*   __restrict__ label,    // [NROWS]
    float* __restrict__ out_logits,     // [NROWS][Tt]
    float* __restrict__ out_pred,       // [NROWS]
    float* __restrict__ loss_out)       // [1]
{
    __shared__ float4 ldsP[Tt * LDS_T];    // 11*200*16 = 35,200 B
    __shared__ float  sCnt[2 * Nn];
    __shared__ float  sScale[Tt];

    int blk = blockIdx.x;
    int b   = blk / BLKS_PER_B;
    int tid = threadIdx.x;

    // Phase A: per-(n,set) mask counts. pcnt flat index = 400*b + n*80 + ch*2 + set.
    if (tid < 2 * Nn) sCnt[tid] = 0.0f;
    __syncthreads();
    for (int i = tid; i < 400; i += 256) {
        float v = pcnt[400 * b + i];
        int n   = i / 80;
        int set = i & 1;
        atomicAdd(&sCnt[2 * n + set], v);
    }
    __syncthreads();
    if (tid < Tt) {
        if (tid == 0) {
            float cO = (float)(KL * Nn);
            #pragma unroll
            for (int k = 0; k < 2 * Nn; ++k) cO -= sCnt[k];
            sScale[0] = 1.0f / (cO + EPS);
        } else {
            sScale[tid] = 1.0f / (sCnt[tid - 1] + EPS);
        }
    }
    __syncthreads();

    // Phase B: stage scaled prototypes into LDS. t=0 -> O = sum_n(All-B-I).
    const float4* bs = (const float4*)bnsum + (size_t)b * Nn * 3 * F4;  // [n][3][F4]
    for (int idx = tid; idx < Tt * F4; idx += 256) {
        int t  = idx / F4;
        int f4 = idx - t * F4;
        float4 val;
        if (t == 0) {
            float sx = 0, sy = 0, sz = 0, sw = 0;
            #pragma unroll
            for (int n = 0; n < Nn; ++n) {
                float4 A  = bs[(n * 3 + 2) * F4 + f4];
                float4 Bv = bs[(n * 3 + 0) * F4 + f4];
                float4 Iv = bs[(n * 3 + 1) * F4 + f4];
                sx += A.x - Bv.x - Iv.x; sy += A.y - Bv.y - Iv.y;
                sz += A.z - Bv.z - Iv.z; sw += A.w - Bv.w - Iv.w;
            }
            val.x = sx; val.y = sy; val.z = sz; val.w = sw;
        } else {
            int n   = (t - 1) >> 1;
            int set = (t - 1) & 1;
            val = bs[(n * 3 + set) * F4 + f4];
        }
        float sc = sScale[t];
        val.x *= sc; val.y *= sc; val.z *= sc; val.w *= sc;
        int s = f4 / SW, j = f4 - SW * s;
        ldsP[t * LDS_T + s * (SW + 1) + j] = val;
    }
    __syncthreads();

    int w    = tid >> 6;
    int lane = tid & 63;
    int p    = lane >> 3;          // 8 rows per wave
    int s    = lane & 7;           // 8 f-slices

    size_t row = (size_t)blk * S3_ROWS + w * 8 + p;
    const float4* q = (const float4*)(query + row * Ff) + s * SW;

    float acc[Tt];
    #pragma unroll
    for (int t = 0; t < Tt; ++t) acc[t] = 0.0f;

    const float4* pb = &ldsP[s * (SW + 1)];
    #pragma unroll
    for (int h = 0; h < 2; ++h) {
        float4 qv[12];
        #pragma unroll
        for (int j = 0; j < 12; ++j) qv[j] = q[h * 12 + j];
        #pragma unroll
        for (int j = 0; j < 12; ++j) {
            float4 u = qv[j];
            int jj = h * 12 + j;
            #pragma unroll
            for (int t = 0; t < Tt; ++t) {
                float4 pv = pb[t * LDS_T + jj];
                float d = acc[t];
                d = fmaf(u.x, pv.x, d); d = fmaf(u.y, pv.y, d);
                d = fmaf(u.z, pv.z, d); d = fmaf(u.w, pv.w, d);
                acc[t] = d;
            }
        }
    }

    // Combine the 8 f-slices (lanes 8p..8p+7) — 3 shuffle levels.
    #pragma unroll
    for (int t = 0; t < Tt; ++t) {
        acc[t] += __shfl_xor(acc[t], 1, 64);
        acc[t] += __shfl_xor(acc[t], 2, 64);
        acc[t] += __shfl_xor(acc[t], 4, 64);
    }

    float wloss = 0.0f;
    if (s == 0) {
        float m = acc[0]; int bt = 0;
        #pragma unroll
        for (int t = 1; t < Tt; ++t) if (acc[t] > m) { m = acc[t]; bt = t; }  // first-max
        float sum = 0.0f;
        #pragma unroll
        for (int t = 0; t < Tt; ++t) sum += __expf(acc[t] - m);
        int lab = label[row];
        float labv = acc[0];
        #pragma unroll
        for (int t = 1; t < Tt; ++t) labv = (lab == t) ? acc[t] : labv;
        #pragma unroll
        for (int t = 0; t < Tt; ++t) out_logits[row * Tt + t] = acc[t];
        out_pred[row] = (float)bt;
        wloss = (m + __logf(sum)) - labv;
    }
    #pragma unroll
    for (int off = 32; off > 0; off >>= 1) wloss += __shfl_xor(wloss, off, 64);
    if (lane == 0) atomicAdd(loss_out, wloss * (1.0f / (float)NROWS));
}

// ---------------- Host launch ----------------
extern "C" void kernel_launch(void* const* d_in, const int* in_sizes, int n_in,
                              void* d_out, int out_size, void* d_ws, size_t ws_size,
                              hipStream_t stream) {
    const float* sup   = (const float*)d_in[0];
    const float* query = (const float*)d_in[1];
    const int*   Bm    = (const int*)d_in[2];
    const int*   Im    = (const int*)d_in[3];
    const int*   lab   = (const int*)d_in[4];

    // ws layout: part [1600][2304] | pcnt [1600][2] | bnsum [40][3][768]
    float* w     = (float*)d_ws;
    float* part  = w;
    float* pcnt  = part + (size_t)S1_NBLK * PART_STRIDE;   // +3,686,400
    float* bnsum = pcnt + 2 * S1_NBLK;                     // +3,200 (16B-aligned)

    float* loss_out   = (float*)d_out;
    float* out_logits = (float*)d_out + 1;
    float* out_pred   = (float*)d_out + 1 + (size_t)NROWS * Tt;

    stage1<<<S1_NBLK, 192, 0, stream>>>(sup, Bm, Im, part, pcnt);
    stage2<<<90, 256, 0, stream>>>(part, bnsum, loss_out);
    stage3<<<S3_NBLK, 256, 0, stream>>>(query, bnsum, pcnt, lab,
                                        out_logits, out_pred, loss_out);
}

// Round 8
// 212.073 us; speedup vs baseline: 1.0041x; 1.0041x over previous
//
#include <hip/hip_runtime.h>
#include <cstdint>
#include <cstddef>

#define EPS 1e-8f

// Fixed problem instance
#define Bsz 8
#define Nn  5
#define Kk  5
#define Ll  128
#define Ff  768
#define Tt  11                 // 2N+1
#define KL  640                // K*L
#define ROWS_PER_B 2560        // N*Q*L
#define NROWS 20480
#define F4  192                // Ff/4
#define BN  40                 // B*N

// ---- stage1 geometry: 32 rows/block, rolling 8-row double buffer ----
#define S1_ROWS 32
#define S1_CH   (KL / S1_ROWS)     // 20 chunks per bn
#define S1_NBLK (BN * S1_CH)       // 800 blocks
#define PART_STRIDE (3 * Ff)       // 2304 floats per record [B|I|All]
#define PART_STRIDE4 (PART_STRIDE / 4)  // 576

typedef float v2f __attribute__((ext_vector_type(2)));

// ---------------- Stage 1: masked partial sums ----------------
// 800 blocks x 192 threads. Lane owns one float4 column. 32 rows per block,
// processed as 4 halves of 8 with double-buffered loads: half h+1 is issued
// BEFORE computing half h, so the memory stream never drains (no lockstep
// burst-then-idle). Records {B,I,All}; O recovered as All-B-I downstream.
__global__ __launch_bounds__(192) void stage1(
    const float* __restrict__ sup,      // [B][N][K][L][F]
    const int*   __restrict__ Bm,       // [B][N][K][L]
    const int*   __restrict__ Im,
    float* __restrict__ part,           // [S1_NBLK][3][Ff]
    float* __restrict__ pcnt)           // [S1_NBLK][2]
{
    int blk = blockIdx.x;
    int bn  = blk / S1_CH;
    int ch  = blk - bn * S1_CH;
    int tid = threadIdx.x;

    const float4* sp = (const float4*)(sup + ((size_t)bn * KL + ch * S1_ROWS) * Ff) + tid;
    const int*    bp = Bm + bn * KL + ch * S1_ROWS;   // block-uniform -> scalar
    const int*    ip = Im + bn * KL + ch * S1_ROWS;

    float4 bufA[8], bufB[8];
    #pragma unroll
    for (int j = 0; j < 8; ++j) bufA[j] = sp[j * F4];   // prologue: half 0

    v2f tB0 = {0.f,0.f}, tB1 = tB0, tI0 = tB0, tI1 = tB0, tA0 = tB0, tA1 = tB0;
    int cB = 0, cI = 0;

    #pragma unroll
    for (int h = 0; h < 4; ++h) {
        // Issue next half's loads before touching current half.
        if (h < 3) {
            if ((h & 1) == 0) {
                #pragma unroll
                for (int j = 0; j < 8; ++j) bufB[j] = sp[((h + 1) * 8 + j) * F4];
            } else {
                #pragma unroll
                for (int j = 0; j < 8; ++j) bufA[j] = sp[((h + 1) * 8 + j) * F4];
            }
        }
        #pragma unroll
        for (int j = 0; j < 8; ++j) {
            int p = h * 8 + j;
            float4 v = ((h & 1) == 0) ? bufA[j] : bufB[j];
            v2f lo = {v.x, v.y};
            v2f hi = {v.z, v.w};
            tA0 += lo; tA1 += hi;
            if (bp[p]) { tB0 += lo; tB1 += hi; ++cB; }
            if (ip[p]) { tI0 += lo; tI1 += hi; ++cI; }
        }
    }

    float4* o = (float4*)(part + (size_t)blk * PART_STRIDE);
    float4 rB = {tB0.x, tB0.y, tB1.x, tB1.y};
    float4 rI = {tI0.x, tI0.y, tI1.x, tI1.y};
    float4 rA = {tA0.x, tA0.y, tA1.x, tA1.y};
    o[tid]          = rB;
    o[F4 + tid]     = rI;
    o[2 * F4 + tid] = rA;

    if (tid == 0) {
        pcnt[2 * (size_t)blk]     = (float)cB;
        pcnt[2 * (size_t)blk + 1] = (float)cI;
    }
}

// ---------------- Stage 2: reduce 20 chunks -> bnsum ----------------
// 90 blocks x 256 = 23,040 threads = one per (bn, set in {B,I,All}, f4).
__global__ __launch_bounds__(256) void stage2(
    const float* __restrict__ part,     // [S1_NBLK][3][Ff]
    float* __restrict__ bnsum,          // [BN][3][Ff]
    float* __restrict__ loss_out)
{
    int gid = blockIdx.x * 256 + threadIdx.x;
    if (gid == 0) loss_out[0] = 0.0f;

    int bn  = gid / (3 * F4);
    int r   = gid - bn * (3 * F4);
    int set = r / F4;
    int f4  = r - set * F4;

    const float4* src = (const float4*)(part + (size_t)bn * S1_CH * PART_STRIDE + set * Ff) + f4;
    float4 s = {0, 0, 0, 0};
    #pragma unroll
    for (int c4 = 0; c4 < S1_CH / 4; ++c4) {
        float4 v[4];
        #pragma unroll
        for (int j = 0; j < 4; ++j) v[j] = src[(size_t)(c4 * 4 + j) * PART_STRIDE4];
        #pragma unroll
        for (int j = 0; j < 4; ++j) {
            s.x += v[j].x; s.y += v[j].y; s.z += v[j].z; s.w += v[j].w;
        }
    }
    ((float4*)bnsum)[((size_t)bn * 3 + set) * F4 + f4] = s;
}

// ---------------- Stage 3: normalize + logits + argmax + NLL ----------------
// 640 blocks x 256 threads (4 waves). Block covers 32 rows; thread = 1 row x
// 1/8-row slice (24 float4). lane = 8*p + s. Query double-buffered qv[2][6]
// (next batch issued before computing current); proto reads batched into an
// explicit pv[11] so the compiler issues all 11 ds_read_b128 then waits once.
#define S3_ROWS 32
#define S3_NBLK (NROWS / S3_ROWS)          // 640
#define BLKS_PER_B (ROWS_PER_B / S3_ROWS)  // 80
#define SL  8                               // slices
#define SW  24                              // float4 per slice
#define LDS_T (SL * (SW + 1))               // 200 float4 per tag

__global__ __launch_bounds__(256) void stage3(
    const float* __restrict__ query,    // [B][2560][Ff]
    const float* __restrict__ bnsum,    // [BN][3][Ff]
    const float* __restrict__ pcnt,     // [S1_NBLK][2]
    const int*   __restrict__ label,    // [NROWS]
    float* __restrict__ out_logits,     // [NROWS][Tt]
    float* __restrict__ out_pred,       // [NROWS]
    float* __restrict__ loss_out)       // [1]
{
    __shared__ float4 ldsP[Tt * LDS_T];    // 35,200 B
    __shared__ float  sCnt[2 * Nn];
    __shared__ float  sScale[Tt];

    int blk = blockIdx.x;
    int b   = blk / BLKS_PER_B;
    int tid = threadIdx.x;

    // Phase A: per-(n,set) mask counts. pcnt flat (per b): n*40 + ch*2 + set.
    if (tid < 2 * Nn) sCnt[tid] = 0.0f;
    __syncthreads();
    if (tid < 200) {
        float v = pcnt[200 * b + tid];
        int n   = tid / 40;
        int set = tid & 1;
        atomicAdd(&sCnt[2 * n + set], v);
    }
    __syncthreads();
    if (tid < Tt) {
        if (tid == 0) {
            float cO = (float)(KL * Nn);
            #pragma unroll
            for (int k = 0; k < 2 * Nn; ++k) cO -= sCnt[k];
            sScale[0] = 1.0f / (cO + EPS);
        } else {
            sScale[tid] = 1.0f / (sCnt[tid - 1] + EPS);
        }
    }
    __syncthreads();

    // Phase B: stage scaled prototypes into LDS. t=0 -> O = sum_n(All-B-I).
    const float4* bs = (const float4*)bnsum + (size_t)b * Nn * 3 * F4;  // [n][3][F4]
    for (int idx = tid; idx < Tt * F4; idx += 256) {
        int t  = idx / F4;
        int f4 = idx - t * F4;
        float4 val;
        if (t == 0) {
            float sx = 0, sy = 0, sz = 0, sw = 0;
            #pragma unroll
            for (int n = 0; n < Nn; ++n) {
                float4 A  = bs[(n * 3 + 2) * F4 + f4];
                float4 Bv = bs[(n * 3 + 0) * F4 + f4];
                float4 Iv = bs[(n * 3 + 1) * F4 + f4];
                sx += A.x - Bv.x - Iv.x; sy += A.y - Bv.y - Iv.y;
                sz += A.z - Bv.z - Iv.z; sw += A.w - Bv.w - Iv.w;
            }
            val.x = sx; val.y = sy; val.z = sz; val.w = sw;
        } else {
            int n   = (t - 1) >> 1;
            int set = (t - 1) & 1;
            val = bs[(n * 3 + set) * F4 + f4];
        }
        float sc = sScale[t];
        val.x *= sc; val.y *= sc; val.z *= sc; val.w *= sc;
        int s = f4 / SW, j = f4 - SW * s;
        ldsP[t * LDS_T + s * (SW + 1) + j] = val;
    }
    __syncthreads();

    int w    = tid >> 6;
    int lane = tid & 63;
    int p    = lane >> 3;          // 8 rows per wave
    int s    = lane & 7;           // 8 f-slices

    size_t row = (size_t)blk * S3_ROWS + w * 8 + p;
    const float4* q = (const float4*)(query + row * Ff) + s * SW;

    float acc[Tt];
    #pragma unroll
    for (int t = 0; t < Tt; ++t) acc[t] = 0.0f;

    const float4* pb = &ldsP[s * (SW + 1)];

    float4 qv[2][6];
    #pragma unroll
    for (int j = 0; j < 6; ++j) qv[0][j] = q[j];      // prologue

    #pragma unroll
    for (int h = 0; h < 4; ++h) {
        if (h < 3) {
            #pragma unroll
            for (int j = 0; j < 6; ++j) qv[(h + 1) & 1][j] = q[(h + 1) * 6 + j];
        }
        #pragma unroll
        for (int j2 = 0; j2 < 6; ++j2) {
            int jj = h * 6 + j2;
            float4 pv[Tt];
            #pragma unroll
            for (int t = 0; t < Tt; ++t) pv[t] = pb[t * LDS_T + jj];
            float4 u = qv[h & 1][j2];
            #pragma unroll
            for (int t = 0; t < Tt; ++t) {
                float d = acc[t];
                d = fmaf(u.x, pv[t].x, d); d = fmaf(u.y, pv[t].y, d);
                d = fmaf(u.z, pv[t].z, d); d = fmaf(u.w, pv[t].w, d);
                acc[t] = d;
            }
        }
    }

    // Combine the 8 f-slices — 3 shuffle levels.
    #pragma unroll
    for (int t = 0; t < Tt; ++t) {
        acc[t] += __shfl_xor(acc[t], 1, 64);
        acc[t] += __shfl_xor(acc[t], 2, 64);
        acc[t] += __shfl_xor(acc[t], 4, 64);
    }

    float wloss = 0.0f;
    if (s == 0) {
        float m = acc[0]; int bt = 0;
        #pragma unroll
        for (int t = 1; t < Tt; ++t) if (acc[t] > m) { m = acc[t]; bt = t; }  // first-max
        float sum = 0.0f;
        #pragma unroll
        for (int t = 0; t < Tt; ++t) sum += __expf(acc[t] - m);
        int lab = label[row];
        float labv = acc[0];
        #pragma unroll
        for (int t = 1; t < Tt; ++t) labv = (lab == t) ? acc[t] : labv;
        #pragma unroll
        for (int t = 0; t < Tt; ++t) out_logits[row * Tt + t] = acc[t];
        out_pred[row] = (float)bt;
        wloss = (m + __logf(sum)) - labv;
    }
    #pragma unroll
    for (int off = 32; off > 0; off >>= 1) wloss += __shfl_xor(wloss, off, 64);
    if (lane == 0) atomicAdd(loss_out, wloss * (1.0f / (float)NROWS));
}

// ---------------- Host launch ----------------
extern "C" void kernel_launch(void* const* d_in, const int* in_sizes, int n_in,
                              void* d_out, int out_size, void* d_ws, size_t ws_size,
                              hipStream_t stream) {
    const float* sup   = (const float*)d_in[0];
    const float* query = (const float*)d_in[1];
    const int*   Bm    = (const int*)d_in[2];
    const int*   Im    = (const int*)d_in[3];
    const int*   lab   = (const int*)d_in[4];

    // ws layout: part [800][2304] | pcnt [800][2] | bnsum [40][3][768]
    float* w     = (float*)d_ws;
    float* part  = w;
    float* pcnt  = part + (size_t)S1_NBLK * PART_STRIDE;   // +1,843,200
    float* bnsum = pcnt + 2 * S1_NBLK;                     // +1,600 (16B-aligned)

    float* loss_out   = (float*)d_out;
    float* out_logits = (float*)d_out + 1;
    float* out_pred   = (float*)d_out + 1 + (size_t)NROWS * Tt;

    stage1<<<S1_NBLK, 192, 0, stream>>>(sup, Bm, Im, part, pcnt);
    stage2<<<90, 256, 0, stream>>>(part, bnsum, loss_out);
    stage3<<<S3_NBLK, 256, 0, stream>>>(query, bnsum, pcnt, lab,
                                        out_logits, out_pred, loss_out);
}